// Round 2
// 650.637 us; speedup vs baseline: 1.0880x; 1.0880x over previous
//
#include <hip/hip_runtime.h>

typedef _Float16 half8 __attribute__((ext_vector_type(8)));
typedef _Float16 half4 __attribute__((ext_vector_type(4)));
typedef _Float16 half2_ __attribute__((ext_vector_type(2)));
typedef float floatx4 __attribute__((ext_vector_type(4)));

__device__ __forceinline__ floatx4 mfma16(half8 a, half8 b, floatx4 c) {
  return __builtin_amdgcn_mfma_f32_16x16x32_f16(a, b, c, 0, 0, 0);
}

constexpr int S_ = 2048;
constexpr int D_ = 64;
constexpr float SCALE = 0.125f;   // 1/sqrt(64)
constexpr int LQ = 72;            // LDS row stride in halves (144 B; 2-way banks = free)

__device__ __forceinline__ half4 cvt_h4(float4 v) {
  half4 h;
  h.x = (_Float16)v.x; h.y = (_Float16)v.y;
  h.z = (_Float16)v.z; h.w = (_Float16)v.w;
  return h;
}

// K tile: row-major [k][d], rows rq and rq+32, vectorized half4 writes.
__device__ __forceinline__ void k_store(_Float16* kbuf, int rq, int cq, float4 f0, float4 f1) {
  *(half4*)&kbuf[rq * LQ + cq]        = cvt_h4(f0);
  *(half4*)&kbuf[(rq + 32) * LQ + cq] = cvt_h4(f1);
}

// V tile: transposed [d][k] with k-block XOR swizzle.
// Element (k,d) lives at d*LQ + 8*((k>>3) ^ ((d>>2)&7)) + (k&7).
// Thread stages rows k=2rq,2rq+1 so each (d) gets a half2 -> ds_write_b32,
// bank = (16L + 4j + (pr ^ 4*(L&7)))%32 -> ~2-way (free) instead of 8-way scatter.
__device__ __forceinline__ void v_store_swz(_Float16* vbuf, int rq, int cq, float4 f0, float4 f1) {
  const float* a0 = (const float*)&f0;
  const float* a1 = (const float*)&f1;
#pragma unroll
  for (int j = 0; j < 4; ++j) {
    int d = cq + j;
    int addr = d * LQ + (((rq >> 2) ^ ((d >> 2) & 7)) << 3) + ((rq & 3) << 1);
    half2_ h; h.x = (_Float16)a0[j]; h.y = (_Float16)a1[j];
    *(half2_*)&vbuf[addr] = h;
  }
}

// One block = one (head, 128-row q-tile). 8 waves; wave w owns q-rows [16w,16w+16).
// grid = 32 heads x 16 q-tiles = 512 = exactly 2 blocks/CU (LDS 73.7 KB/block).
__global__ __launch_bounds__(512, 4)
void attn_fused(const float* __restrict__ Q, const float* __restrict__ K,
                const float* __restrict__ V, float* __restrict__ O,
                float* __restrict__ P) {
  __shared__ _Float16 Qs[128 * LQ];
  __shared__ _Float16 Ks[2][64 * LQ];   // double-buffered
  __shared__ _Float16 Vs[2][64 * LQ];   // double-buffered, swizzled-transposed
  __shared__ _Float16 Ps[128 * LQ];

  const int tid  = threadIdx.x;
  const int wave = tid >> 6;
  const int lane = tid & 63;
  const int l16  = lane & 15;
  const int quad = lane >> 4;

  const int bh = blockIdx.x >> 4;   // 32 heads
  const int qt = blockIdx.x & 15;   // 16 q-tiles per head

  const float* Qg = Q + ((size_t)bh * S_ + qt * 128) * D_;
  const float* Kg = K + (size_t)bh * S_ * D_;
  const float* Vg = V + (size_t)bh * S_ * D_;
  float* Og = O + ((size_t)bh * S_ + qt * 128) * D_;
  float* Pg = P + (size_t)bh * S_ * S_ + (size_t)qt * 128 * S_;

  const int rq = tid >> 4;          // 0..31
  const int cq = (tid & 15) << 2;   // 0..60

  // ---- prologue: stage Q (128x64), K0, V0 ----
#pragma unroll
  for (int i = 0; i < 4; ++i) {
    int r = rq + (i << 5);
    float4 v = *(const float4*)(Qg + r * D_ + cq);
    *(half4*)&Qs[r * LQ + cq] = cvt_h4(v);
  }
  {
    float4 k0 = *(const float4*)(Kg + rq * D_ + cq);
    float4 k1 = *(const float4*)(Kg + (rq + 32) * D_ + cq);
    k_store(Ks[0], rq, cq, k0, k1);
    float4 v0 = *(const float4*)(Vg + (2 * rq) * D_ + cq);
    float4 v1 = *(const float4*)(Vg + (2 * rq + 1) * D_ + cq);
    v_store_swz(Vs[0], rq, cq, v0, v1);
  }
  __syncthreads();

  // Q A-fragments are k-invariant: hoist. A[m=l16][k=quad*8+j]
  const int arow = wave * 16 + l16;
  const half8 qa0 = *(const half8*)&Qs[arow * LQ + quad * 8];
  const half8 qa1 = *(const half8*)&Qs[arow * LQ + quad * 8 + 32];

  // ---- phase 1: row sums of exp(scores); prefetch next K tile during compute ----
  float rs0 = 0.f, rs1 = 0.f, rs2 = 0.f, rs3 = 0.f;   // rows quad*4 + {0..3}
  for (int kt = 0; kt < 32; ++kt) {
    const int cur = kt & 1;
    float4 pk0, pk1;
    const bool pf = (kt < 31);
    if (pf) {
      const float* Kt = Kg + (size_t)(kt + 1) * 64 * D_;
      pk0 = *(const float4*)(Kt + rq * D_ + cq);
      pk1 = *(const float4*)(Kt + (rq + 32) * D_ + cq);
    }
#pragma unroll
    for (int cb = 0; cb < 4; ++cb) {
      half8 b0 = *(const half8*)&Ks[cur][(cb * 16 + l16) * LQ + quad * 8];
      half8 b1 = *(const half8*)&Ks[cur][(cb * 16 + l16) * LQ + quad * 8 + 32];
      floatx4 acc = {0.f, 0.f, 0.f, 0.f};
      acc = mfma16(qa0, b0, acc);
      acc = mfma16(qa1, b1, acc);
      rs0 += __expf(acc[0] * SCALE);
      rs1 += __expf(acc[1] * SCALE);
      rs2 += __expf(acc[2] * SCALE);
      rs3 += __expf(acc[3] * SCALE);
    }
    if (pf) k_store(Ks[cur ^ 1], rq, cq, pk0, pk1);   // other buffer: no race with readers
    __syncthreads();                                   // 1 barrier per k-tile
  }
  rs0 += __shfl_xor(rs0, 1); rs0 += __shfl_xor(rs0, 2); rs0 += __shfl_xor(rs0, 4); rs0 += __shfl_xor(rs0, 8);
  rs1 += __shfl_xor(rs1, 1); rs1 += __shfl_xor(rs1, 2); rs1 += __shfl_xor(rs1, 4); rs1 += __shfl_xor(rs1, 8);
  rs2 += __shfl_xor(rs2, 1); rs2 += __shfl_xor(rs2, 2); rs2 += __shfl_xor(rs2, 4); rs2 += __shfl_xor(rs2, 8);
  rs3 += __shfl_xor(rs3, 1); rs3 += __shfl_xor(rs3, 2); rs3 += __shfl_xor(rs3, 4); rs3 += __shfl_xor(rs3, 8);
  const float inv0 = 1.f / rs0, inv1 = 1.f / rs1, inv2 = 1.f / rs2, inv3 = 1.f / rs3;

  // ---- phase 2 prologue: restage K0, V0 ----
  {
    float4 k0 = *(const float4*)(Kg + rq * D_ + cq);
    float4 k1 = *(const float4*)(Kg + (rq + 32) * D_ + cq);
    float4 v0 = *(const float4*)(Vg + (2 * rq) * D_ + cq);
    float4 v1 = *(const float4*)(Vg + (2 * rq + 1) * D_ + cq);
    __syncthreads();                 // phase-1 readers of Ks done before overwrite
    k_store(Ks[0], rq, cq, k0, k1);
    v_store_swz(Vs[0], rq, cq, v0, v1);
  }
  __syncthreads();

  // ---- phase 2: recompute scores, write P, accumulate O += P V ----
  floatx4 oacc[4];
#pragma unroll
  for (int cb = 0; cb < 4; ++cb) { floatx4 z = {0.f, 0.f, 0.f, 0.f}; oacc[cb] = z; }

  for (int kt = 0; kt < 32; ++kt) {
    const int cur = kt & 1;
    const bool pf = (kt < 31);
    float4 pk0, pk1, pv0, pv1;
    if (pf) {                         // issue next-tile loads early (latency hides under QK+PV)
      const float* Kt = Kg + (size_t)(kt + 1) * 64 * D_;
      const float* Vt = Vg + (size_t)(kt + 1) * 64 * D_;
      pk0 = *(const float4*)(Kt + rq * D_ + cq);
      pk1 = *(const float4*)(Kt + (rq + 32) * D_ + cq);
      pv0 = *(const float4*)(Vt + (2 * rq) * D_ + cq);
      pv1 = *(const float4*)(Vt + (2 * rq + 1) * D_ + cq);
    }
    // --- QK^T + softmax-scale -> Ps ---
#pragma unroll
    for (int cb = 0; cb < 4; ++cb) {
      half8 b0 = *(const half8*)&Ks[cur][(cb * 16 + l16) * LQ + quad * 8];
      half8 b1 = *(const half8*)&Ks[cur][(cb * 16 + l16) * LQ + quad * 8 + 32];
      floatx4 acc = {0.f, 0.f, 0.f, 0.f};
      acc = mfma16(qa0, b0, acc);
      acc = mfma16(qa1, b1, acc);
      float p0 = __expf(acc[0] * SCALE) * inv0;
      float p1 = __expf(acc[1] * SCALE) * inv1;
      float p2 = __expf(acc[2] * SCALE) * inv2;
      float p3 = __expf(acc[3] * SCALE) * inv3;
      int col = cb * 16 + l16;        // C layout: col=lane&15, row=quad*4+reg
      Ps[(wave * 16 + quad * 4 + 0) * LQ + col] = (_Float16)p0;
      Ps[(wave * 16 + quad * 4 + 1) * LQ + col] = (_Float16)p1;
      Ps[(wave * 16 + quad * 4 + 2) * LQ + col] = (_Float16)p2;
      Ps[(wave * 16 + quad * 4 + 3) * LQ + col] = (_Float16)p3;
    }
    __syncthreads();                  // sync1: Ps complete

    // --- coalesced nontemporal fp32 write of the 128x64 P tile ---
    float* Pt = Pg + kt * 64;
#pragma unroll
    for (int i = 0; i < 4; ++i) {
      int r = rq + (i << 5);
      half4 h = *(const half4*)&Ps[r * LQ + cq];
      floatx4 o;
      o[0] = (float)h.x; o[1] = (float)h.y; o[2] = (float)h.z; o[3] = (float)h.w;
      __builtin_nontemporal_store(o, (floatx4*)(Pt + (size_t)r * S_ + cq));
    }

    // --- PV: A = P rows (LDS round-trip did C->A layout), B = V^T via swizzled reads ---
    half8 pa0 = *(const half8*)&Ps[arow * LQ + quad * 8];
    half8 pa1 = *(const half8*)&Ps[arow * LQ + quad * 8 + 32];
#pragma unroll
    for (int cb = 0; cb < 4; ++cb) {
      const int dd  = cb * 16 + l16;
      const int hsw = (dd >> 2) & 7;
      half8 vb0 = *(const half8*)&Vs[cur][dd * LQ + ((quad ^ hsw) << 3)];
      half8 vb1 = *(const half8*)&Vs[cur][dd * LQ + (((quad + 4) ^ hsw) << 3)];
      oacc[cb] = mfma16(pa0, vb0, oacc[cb]);
      oacc[cb] = mfma16(pa1, vb1, oacc[cb]);
    }

    if (pf) {                         // write prefetched tile into the other buffer
      k_store(Ks[cur ^ 1], rq, cq, pk0, pk1);
      v_store_swz(Vs[cur ^ 1], rq, cq, pv0, pv1);
    }
    __syncthreads();                  // sync2: writes visible; Ps reads done
  }

  // ---- epilogue: write O (C layout direct; only 16.8 MB) ----
#pragma unroll
  for (int cb = 0; cb < 4; ++cb) {
#pragma unroll
    for (int r = 0; r < 4; ++r) {
      Og[(size_t)(wave * 16 + quad * 4 + r) * D_ + cb * 16 + l16] = oacc[cb][r];
    }
  }
}

extern "C" void kernel_launch(void* const* d_in, const int* in_sizes, int n_in,
                              void* d_out, int out_size, void* d_ws, size_t ws_size,
                              hipStream_t stream) {
  const float* q = (const float*)d_in[0];
  const float* k = (const float*)d_in[1];
  const float* v = (const float*)d_in[2];
  float* out = (float*)d_out;                       // [2,16,2048,64]
  float* p   = (float*)d_out + (size_t)2 * 16 * 2048 * 64;  // [2,16,2048,2048]
  dim3 grid(32 * 16);   // 32 heads x 16 q-tiles of 128 rows
  dim3 block(512);
  attn_fused<<<grid, block, 0, stream>>>(q, k, v, out, p);
}